// Round 4
// baseline (815.055 us; speedup 1.0000x reference)
//
#include <hip/hip_runtime.h>

#define NIMG 16
#define NC 3
#define H 256
#define W 256
#define HW (H * W)
#define NS 25          // 5x5 per-pixel kernel
#define TH 16
#define TW 16
#define SRH (TH + 10)  // s-tile region: fac halo(2) + conv halo(3) each side
#define SRW (TW + 10)
#define SRN (SRH * SRW)            // 676
#define MRH (TH + 4)   // q region: fac halo(2) each side
#define MRW (TW + 4)
#define MRN (MRH * MRW)            // 400
#define NTHREADS 256
#define NHALO (SRN - TH * TW)      // 420 halo-only region points

// round-to-nearest-even fp32 -> bf16 (as u16)
__device__ __forceinline__ unsigned bf16r(float x) {
    union { float f; unsigned u; } c; c.f = x;
    return (c.u + 0x7FFFu + ((c.u >> 16) & 1u)) >> 16;
}
__device__ __forceinline__ float bf_hi(unsigned u) {  // high 16 bits -> float
    union { unsigned u; float f; } c; c.u = u & 0xFFFF0000u; return c.f;
}
__device__ __forceinline__ float bf_lo(unsigned u) {  // low 16 bits -> float
    union { unsigned u; float f; } c; c.u = u << 16; return c.f;
}

// Fused kernel, v3 (resubmit — R3 bench was an infra failure, kernel never ran).
// Latency-bound fix (rocprof r2: 17% HBM, 30% VALU, 22% occ -> nothing
// saturated; 4 blocks/CU lockstep on barriers was the wall).
//  - 16x16 tiles, PPT=1: pk reg cache 100->25 VGPR. launch_bounds(256,6)
//    targets <=85 VGPR -> 6 blocks/CU resident (24 waves, 1.5x), and the
//    4096-block grid gives 16 assigned blocks/CU -> block turnover hides
//    barrier/load stalls (desync), which 4/4 resident couldn't.
//  - LDS 8.7 KB/block (was 24 KB).
//  - Same ownership trick: thread keeps its center pixel's 25 perpix values
//    in VGPRs from the phase-1 reduction -> phase-3 fac does zero global loads.
//  - XCD-chunked swizzle, bijective (4096 % 8 == 0).
//  - Arithmetic order per output identical to v2 -> bit-identical result.
__global__ __launch_bounds__(NTHREADS, 6)
void reblur_fused(const float* __restrict__ blur_info,
                  const float* __restrict__ pp0,
                  const float* __restrict__ pp1,
                  const float* __restrict__ pp2,
                  const float* __restrict__ wt0,
                  const float* __restrict__ wt1,
                  const float* __restrict__ wt2,
                  float* __restrict__ out)
{
    __shared__ unsigned s_l[SRN];        // 2.7 KB packed (sum,max) bf16 pair
    __shared__ float q[NC][MRN];         // 4.8 KB  q = mask*blur
    __shared__ float wts[3][98];         // 1.2 KB, all branch conv weights

    const int tid = threadIdx.x;

    // XCD-chunked swizzle: 4096 blocks, 512 contiguous tiles per XCD.
    const int id  = blockIdx.x + (blockIdx.y << 4) + (blockIdx.z << 8);
    const int sid = ((id & 7) << 9) + (id >> 3);
    const int n   = sid >> 8;
    const int h0  = ((sid >> 4) & 15) * TH;
    const int w0  = (sid & 15) * TW;

    // all 3 branches' weights, 1/25 mean factor folded into avg-channel taps
    if (tid < 98) {
        float sc = (tid < 49) ? 0.04f : 1.0f;
        wts[0][tid] = wt0[tid] * sc;
        wts[1][tid] = wt1[tid] * sc;
        wts[2][tid] = wt2[tid] * sc;
    }

    float facc0 = 0.f, facc1 = 0.f, facc2 = 0.f;

    const size_t nbase = (size_t)n * NS * HW;
    const int r = tid >> 4, c = tid & 15;          // this thread's center pixel

    float pk[NS];   // statically indexed only -> stays in VGPRs

    #pragma unroll 1
    for (int b = 0; b < 3; ++b) {
        const float* pb = (b == 0) ? pp0 : ((b == 1) ? pp1 : pp2);
        pb += nbase;

        // ---- phase 1a: center 16x16 — stream 25 ch, reduce AND keep in regs
        {
            const float* p = pb + (h0 + r) * W + (w0 + c);
            float v = p[0];
            pk[0] = v;
            float sm = v, mx = v;
            #pragma unroll
            for (int s = 1; s < NS; ++s) {
                v = p[s * HW];
                pk[s] = v;
                sm += v; mx = fmaxf(mx, v);
            }
            s_l[(r + 5) * SRW + (c + 5)] = (bf16r(sm) << 16) | bf16r(mx);
        }

        // ---- phase 1b: halo-only points (420) — reduce, no storage
        for (int m = tid; m < NHALO; m += NTHREADS) {
            int rr, cc;
            if (m < 130)      { rr = m / 26;              cc = m % 26; }
            else if (m < 260) { int t = m - 130; rr = 21 + t / 26; cc = t % 26; }
            else              { int t = m - 260; rr = 5 + t / 10;
                                int c2 = t % 10; cc = (c2 < 5) ? c2 : c2 + 16; }
            const int gh = h0 - 5 + rr, gw = w0 - 5 + cc;
            unsigned u = 0;
            if ((unsigned)gh < H && (unsigned)gw < W) {
                const float* p = pb + gh * W + gw;
                float v = p[0];
                float sm = v, mx = v;
                #pragma unroll
                for (int s = 1; s < NS; ++s) {
                    v = p[s * HW];
                    sm += v; mx = fmaxf(mx, v);
                }
                u = (bf16r(sm) << 16) | bf16r(mx);
            }
            s_l[rr * SRW + cc] = u;
        }
        __syncthreads();

        // ---- phase 2: conv7x7 + sigmoid -> q = mask*blur over 20x20
        const float* wb = &wts[b][0];
        for (int i = tid; i < MRN; i += NTHREADS) {
            int rr = i / MRW, cc = i % MRW;
            float a = 0.f;
            #pragma unroll
            for (int j = 0; j < 7; ++j) {
                #pragma unroll
                for (int t = 0; t < 7; ++t) {
                    unsigned u = s_l[(rr + j) * SRW + cc + t];
                    a += bf_hi(u) * wb[j * 7 + t] + bf_lo(u) * wb[49 + j * 7 + t];
                }
            }
            float m = 1.f / (1.f + __expf(-a));
            int gh = h0 - 2 + rr, gw = w0 - 2 + cc;
            bool inb = (unsigned)gh < H && (unsigned)gw < W;
            int gi = gh * W + gw;
            #pragma unroll
            for (int cch = 0; cch < NC; ++cch) {
                float bv = inb ? blur_info[(n * NC + cch) * HW + gi] : 0.f;  // feat zero-pad
                q[cch][i] = m * bv;
            }
        }
        __syncthreads();

        // ---- phase 3: fac from REGISTERS — zero global traffic
        {
            const int qc = (r + 2) * MRW + c + 2;
            float f0 = -q[0][qc], f1 = -q[1][qc], f2 = -q[2][qc];
            #pragma unroll
            for (int s = 0; s < NS; ++s) {
                const int qi = (r + s / 5) * MRW + c + (s % 5);
                const float v = pk[s];
                f0 += v * q[0][qi];
                f1 += v * q[1][qi];
                f2 += v * q[2][qi];
            }
            facc0 += f0; facc1 += f1; facc2 += f2;
        }
        // next branch's phase-1 writes s_l (not read by phase 3); q overwrite
        // is fenced by the post-phase-1 barrier of the next branch -> race-free.
    }

    // ---- epilogue: out = blur + (f_1+f_2+f_3)/3  (blur*(1-m) folded via -q_center)
    const float inv3 = 1.f / 3.f;
    const int gi = (h0 + r) * W + (w0 + c);
    out[(n * NC + 0) * HW + gi] = blur_info[(n * NC + 0) * HW + gi] + facc0 * inv3;
    out[(n * NC + 1) * HW + gi] = blur_info[(n * NC + 1) * HW + gi] + facc1 * inv3;
    out[(n * NC + 2) * HW + gi] = blur_info[(n * NC + 2) * HW + gi] + facc2 * inv3;
}

extern "C" void kernel_launch(void* const* d_in, const int* in_sizes, int n_in,
                              void* d_out, int out_size, void* d_ws, size_t ws_size,
                              hipStream_t stream) {
    const float* blur = (const float*)d_in[0];
    float* out = (float*)d_out;

    dim3 grid(W / TW, H / TH, NIMG);     // 16 x 16 x 16 = 4096 blocks
    reblur_fused<<<grid, NTHREADS, 0, stream>>>(
        blur,
        (const float*)d_in[1], (const float*)d_in[2], (const float*)d_in[3],
        (const float*)d_in[4], (const float*)d_in[5], (const float*)d_in[6],
        out);
}

// Round 5
// 489.097 us; speedup vs baseline: 1.6664x; 1.6664x over previous
//
#include <hip/hip_runtime.h>

#define NIMG 16
#define NC 3
#define H 256
#define W 256
#define HW (H * W)
#define NS 25          // 5x5 per-pixel kernel
#define TH 16
#define TW 16
#define SRH (TH + 10)  // s-tile region: fac halo(2) + conv halo(3) each side
#define SRW (TW + 10)
#define SRN (SRH * SRW)            // 676
#define MRH (TH + 4)   // q region: fac halo(2) each side
#define MRW (TW + 4)
#define MRN (MRH * MRW)            // 400
#define NTHREADS 256
#define NHALO (SRN - TH * TW)      // 420 halo-only region points

// round-to-nearest-even fp32 -> bf16 (as u16)
__device__ __forceinline__ unsigned bf16r(float x) {
    union { float f; unsigned u; } c; c.f = x;
    return (c.u + 0x7FFFu + ((c.u >> 16) & 1u)) >> 16;
}
__device__ __forceinline__ float bf_hi(unsigned u) {  // high 16 bits -> float
    union { unsigned u; float f; } c; c.u = u & 0xFFFF0000u; return c.f;
}
__device__ __forceinline__ float bf_lo(unsigned u) {  // low 16 bits -> float
    union { unsigned u; float f; } c; c.u = u << 16; return c.f;
}

// Fused kernel, v4. v3's launch_bounds(256,6) forced VGPR=40 -> pk[25]
// spilled to scratch (rocprof: WRITE 958 MB vs 12.6 MB output, FETCH 1.07 GB,
// VALUBusy 13%) -> 622 us. Fix: (256,4) = 128-VGPR budget, no spills.
//  - 16x16 tiles, PPT=1: pk reg cache 25 VGPR; ~64-90 total -> fits.
//  - 4096-block grid = 16 assigned blocks/CU with 4-6 resident -> block
//    turnover desyncs barriers (v2's 4-assigned/4-resident had none).
//  - LDS 8.7 KB/block.
//  - Thread keeps its center pixel's 25 perpix values in VGPRs from the
//    phase-1 reduction -> phase-3 fac does zero global loads.
//  - XCD-chunked swizzle, bijective (4096 % 8 == 0).
//  - Arithmetic order per output identical to v2/v3 -> bit-identical result.
__global__ __launch_bounds__(NTHREADS, 4)
void reblur_fused(const float* __restrict__ blur_info,
                  const float* __restrict__ pp0,
                  const float* __restrict__ pp1,
                  const float* __restrict__ pp2,
                  const float* __restrict__ wt0,
                  const float* __restrict__ wt1,
                  const float* __restrict__ wt2,
                  float* __restrict__ out)
{
    __shared__ unsigned s_l[SRN];        // 2.7 KB packed (sum,max) bf16 pair
    __shared__ float q[NC][MRN];         // 4.8 KB  q = mask*blur
    __shared__ float wts[3][98];         // 1.2 KB, all branch conv weights

    const int tid = threadIdx.x;

    // XCD-chunked swizzle: 4096 blocks, 512 contiguous tiles per XCD.
    const int id  = blockIdx.x + (blockIdx.y << 4) + (blockIdx.z << 8);
    const int sid = ((id & 7) << 9) + (id >> 3);
    const int n   = sid >> 8;
    const int h0  = ((sid >> 4) & 15) * TH;
    const int w0  = (sid & 15) * TW;

    // all 3 branches' weights, 1/25 mean factor folded into avg-channel taps
    if (tid < 98) {
        float sc = (tid < 49) ? 0.04f : 1.0f;
        wts[0][tid] = wt0[tid] * sc;
        wts[1][tid] = wt1[tid] * sc;
        wts[2][tid] = wt2[tid] * sc;
    }

    float facc0 = 0.f, facc1 = 0.f, facc2 = 0.f;

    const size_t nbase = (size_t)n * NS * HW;
    const int r = tid >> 4, c = tid & 15;          // this thread's center pixel

    float pk[NS];   // statically indexed only -> stays in VGPRs

    #pragma unroll 1
    for (int b = 0; b < 3; ++b) {
        const float* pb = (b == 0) ? pp0 : ((b == 1) ? pp1 : pp2);
        pb += nbase;

        // ---- phase 1a: center 16x16 — stream 25 ch, reduce AND keep in regs
        {
            const float* p = pb + (h0 + r) * W + (w0 + c);
            float v = p[0];
            pk[0] = v;
            float sm = v, mx = v;
            #pragma unroll
            for (int s = 1; s < NS; ++s) {
                v = p[s * HW];
                pk[s] = v;
                sm += v; mx = fmaxf(mx, v);
            }
            s_l[(r + 5) * SRW + (c + 5)] = (bf16r(sm) << 16) | bf16r(mx);
        }

        // ---- phase 1b: halo-only points (420) — reduce, no storage
        for (int m = tid; m < NHALO; m += NTHREADS) {
            int rr, cc;
            if (m < 130)      { rr = m / 26;              cc = m % 26; }
            else if (m < 260) { int t = m - 130; rr = 21 + t / 26; cc = t % 26; }
            else              { int t = m - 260; rr = 5 + t / 10;
                                int c2 = t % 10; cc = (c2 < 5) ? c2 : c2 + 16; }
            const int gh = h0 - 5 + rr, gw = w0 - 5 + cc;
            unsigned u = 0;
            if ((unsigned)gh < H && (unsigned)gw < W) {
                const float* p = pb + gh * W + gw;
                float v = p[0];
                float sm = v, mx = v;
                #pragma unroll
                for (int s = 1; s < NS; ++s) {
                    v = p[s * HW];
                    sm += v; mx = fmaxf(mx, v);
                }
                u = (bf16r(sm) << 16) | bf16r(mx);
            }
            s_l[rr * SRW + cc] = u;
        }
        __syncthreads();

        // ---- phase 2: conv7x7 + sigmoid -> q = mask*blur over 20x20
        const float* wb = &wts[b][0];
        for (int i = tid; i < MRN; i += NTHREADS) {
            int rr = i / MRW, cc = i % MRW;
            float a = 0.f;
            #pragma unroll
            for (int j = 0; j < 7; ++j) {
                #pragma unroll
                for (int t = 0; t < 7; ++t) {
                    unsigned u = s_l[(rr + j) * SRW + cc + t];
                    a += bf_hi(u) * wb[j * 7 + t] + bf_lo(u) * wb[49 + j * 7 + t];
                }
            }
            float m = 1.f / (1.f + __expf(-a));
            int gh = h0 - 2 + rr, gw = w0 - 2 + cc;
            bool inb = (unsigned)gh < H && (unsigned)gw < W;
            int gi = gh * W + gw;
            #pragma unroll
            for (int cch = 0; cch < NC; ++cch) {
                float bv = inb ? blur_info[(n * NC + cch) * HW + gi] : 0.f;  // feat zero-pad
                q[cch][i] = m * bv;
            }
        }
        __syncthreads();

        // ---- phase 3: fac from REGISTERS — zero global traffic
        {
            const int qc = (r + 2) * MRW + c + 2;
            float f0 = -q[0][qc], f1 = -q[1][qc], f2 = -q[2][qc];
            #pragma unroll
            for (int s = 0; s < NS; ++s) {
                const int qi = (r + s / 5) * MRW + c + (s % 5);
                const float v = pk[s];
                f0 += v * q[0][qi];
                f1 += v * q[1][qi];
                f2 += v * q[2][qi];
            }
            facc0 += f0; facc1 += f1; facc2 += f2;
        }
        // next branch's phase-1 writes s_l (not read by phase 3); q overwrite
        // is fenced by the post-phase-1 barrier of the next branch -> race-free.
    }

    // ---- epilogue: out = blur + (f_1+f_2+f_3)/3  (blur*(1-m) folded via -q_center)
    const float inv3 = 1.f / 3.f;
    const int gi = (h0 + r) * W + (w0 + c);
    out[(n * NC + 0) * HW + gi] = blur_info[(n * NC + 0) * HW + gi] + facc0 * inv3;
    out[(n * NC + 1) * HW + gi] = blur_info[(n * NC + 1) * HW + gi] + facc1 * inv3;
    out[(n * NC + 2) * HW + gi] = blur_info[(n * NC + 2) * HW + gi] + facc2 * inv3;
}

extern "C" void kernel_launch(void* const* d_in, const int* in_sizes, int n_in,
                              void* d_out, int out_size, void* d_ws, size_t ws_size,
                              hipStream_t stream) {
    const float* blur = (const float*)d_in[0];
    float* out = (float*)d_out;

    dim3 grid(W / TW, H / TH, NIMG);     // 16 x 16 x 16 = 4096 blocks
    reblur_fused<<<grid, NTHREADS, 0, stream>>>(
        blur,
        (const float*)d_in[1], (const float*)d_in[2], (const float*)d_in[3],
        (const float*)d_in[4], (const float*)d_in[5], (const float*)d_in[6],
        out);
}

// Round 6
// 387.239 us; speedup vs baseline: 2.1048x; 1.2630x over previous
//
#include <hip/hip_runtime.h>

#define NIMG 16
#define NC 3
#define H 256
#define W 256
#define HW (H * W)
#define NS 25          // 5x5 per-pixel kernel
#define TH 16
#define TW 16
#define SRH (TH + 10)  // s-tile region: fac halo(2) + conv halo(3) each side
#define SRW (TW + 10)
#define SRN (SRH * SRW)            // 676
#define MRH (TH + 4)   // q region: fac halo(2) each side
#define MRW (TW + 4)
#define MRN (MRH * MRW)            // 400
#define NTHREADS 256
#define NHALO (SRN - TH * TW)      // 420 halo-only region points

// round-to-nearest-even fp32 -> bf16 (as u16)
__device__ __forceinline__ unsigned bf16r(float x) {
    union { float f; unsigned u; } c; c.f = x;
    return (c.u + 0x7FFFu + ((c.u >> 16) & 1u)) >> 16;
}
__device__ __forceinline__ float bf_hi(unsigned u) {  // high 16 bits -> float
    union { unsigned u; float f; } c; c.u = u & 0xFFFF0000u; return c.f;
}
__device__ __forceinline__ float bf_lo(unsigned u) {  // low 16 bits -> float
    union { unsigned u; float f; } c; c.u = u << 16; return c.f;
}

// Fused kernel, v5. Register-budget fix.
// Toolchain empirical: launch_bounds(256,N) caps VGPR at ~256/N
//   (v2: N=2 -> 128, v3: N=6 -> 40, v4: N=4 -> 64). At 64 VGPR pk[25]
//   spilled (WRITE 284 MB vs 12.6 MB output). N=2 restores the proven
//   128-VGPR zero-spill budget; this 16x16 kernel needs ~75-95.
//  - 16x16 tiles, PPT=1: pk reg cache 25 VGPR.
//  - 4096-block grid = 16 assigned blocks/CU, ~4 resident -> staggered
//    starts + turnover desync barriers (v2's 4/4 lockstep was the wall).
//  - LDS 8.7 KB/block.
//  - Thread keeps its center pixel's 25 perpix values in VGPRs from the
//    phase-1 reduction -> phase-3 fac does zero global loads.
//  - XCD-chunked swizzle, bijective (4096 % 8 == 0).
//  - Arithmetic order per output identical to v2/v3/v4 -> bit-identical.
__global__ __launch_bounds__(NTHREADS, 2)
void reblur_fused(const float* __restrict__ blur_info,
                  const float* __restrict__ pp0,
                  const float* __restrict__ pp1,
                  const float* __restrict__ pp2,
                  const float* __restrict__ wt0,
                  const float* __restrict__ wt1,
                  const float* __restrict__ wt2,
                  float* __restrict__ out)
{
    __shared__ unsigned s_l[SRN];        // 2.7 KB packed (sum,max) bf16 pair
    __shared__ float q[NC][MRN];         // 4.8 KB  q = mask*blur
    __shared__ float wts[3][98];         // 1.2 KB, all branch conv weights

    const int tid = threadIdx.x;

    // XCD-chunked swizzle: 4096 blocks, 512 contiguous tiles per XCD.
    const int id  = blockIdx.x + (blockIdx.y << 4) + (blockIdx.z << 8);
    const int sid = ((id & 7) << 9) + (id >> 3);
    const int n   = sid >> 8;
    const int h0  = ((sid >> 4) & 15) * TH;
    const int w0  = (sid & 15) * TW;

    // all 3 branches' weights, 1/25 mean factor folded into avg-channel taps
    if (tid < 98) {
        float sc = (tid < 49) ? 0.04f : 1.0f;
        wts[0][tid] = wt0[tid] * sc;
        wts[1][tid] = wt1[tid] * sc;
        wts[2][tid] = wt2[tid] * sc;
    }

    float facc0 = 0.f, facc1 = 0.f, facc2 = 0.f;

    const size_t nbase = (size_t)n * NS * HW;
    const int r = tid >> 4, c = tid & 15;          // this thread's center pixel

    float pk[NS];   // statically indexed only -> stays in VGPRs

    #pragma unroll 1
    for (int b = 0; b < 3; ++b) {
        const float* pb = (b == 0) ? pp0 : ((b == 1) ? pp1 : pp2);
        pb += nbase;

        // ---- phase 1a: center 16x16 — stream 25 ch, reduce AND keep in regs
        {
            const float* p = pb + (h0 + r) * W + (w0 + c);
            float v = p[0];
            pk[0] = v;
            float sm = v, mx = v;
            #pragma unroll
            for (int s = 1; s < NS; ++s) {
                v = p[s * HW];
                pk[s] = v;
                sm += v; mx = fmaxf(mx, v);
            }
            s_l[(r + 5) * SRW + (c + 5)] = (bf16r(sm) << 16) | bf16r(mx);
        }

        // ---- phase 1b: halo-only points (420) — reduce, no storage
        for (int m = tid; m < NHALO; m += NTHREADS) {
            int rr, cc;
            if (m < 130)      { rr = m / 26;              cc = m % 26; }
            else if (m < 260) { int t = m - 130; rr = 21 + t / 26; cc = t % 26; }
            else              { int t = m - 260; rr = 5 + t / 10;
                                int c2 = t % 10; cc = (c2 < 5) ? c2 : c2 + 16; }
            const int gh = h0 - 5 + rr, gw = w0 - 5 + cc;
            unsigned u = 0;
            if ((unsigned)gh < H && (unsigned)gw < W) {
                const float* p = pb + gh * W + gw;
                float v = p[0];
                float sm = v, mx = v;
                #pragma unroll
                for (int s = 1; s < NS; ++s) {
                    v = p[s * HW];
                    sm += v; mx = fmaxf(mx, v);
                }
                u = (bf16r(sm) << 16) | bf16r(mx);
            }
            s_l[rr * SRW + cc] = u;
        }
        __syncthreads();

        // ---- phase 2: conv7x7 + sigmoid -> q = mask*blur over 20x20
        const float* wb = &wts[b][0];
        for (int i = tid; i < MRN; i += NTHREADS) {
            int rr = i / MRW, cc = i % MRW;
            float a = 0.f;
            #pragma unroll
            for (int j = 0; j < 7; ++j) {
                #pragma unroll
                for (int t = 0; t < 7; ++t) {
                    unsigned u = s_l[(rr + j) * SRW + cc + t];
                    a += bf_hi(u) * wb[j * 7 + t] + bf_lo(u) * wb[49 + j * 7 + t];
                }
            }
            float m = 1.f / (1.f + __expf(-a));
            int gh = h0 - 2 + rr, gw = w0 - 2 + cc;
            bool inb = (unsigned)gh < H && (unsigned)gw < W;
            int gi = gh * W + gw;
            #pragma unroll
            for (int cch = 0; cch < NC; ++cch) {
                float bv = inb ? blur_info[(n * NC + cch) * HW + gi] : 0.f;  // feat zero-pad
                q[cch][i] = m * bv;
            }
        }
        __syncthreads();

        // ---- phase 3: fac from REGISTERS — zero global traffic
        {
            const int qc = (r + 2) * MRW + c + 2;
            float f0 = -q[0][qc], f1 = -q[1][qc], f2 = -q[2][qc];
            #pragma unroll
            for (int s = 0; s < NS; ++s) {
                const int qi = (r + s / 5) * MRW + c + (s % 5);
                const float v = pk[s];
                f0 += v * q[0][qi];
                f1 += v * q[1][qi];
                f2 += v * q[2][qi];
            }
            facc0 += f0; facc1 += f1; facc2 += f2;
        }
        // next branch's phase-1 writes s_l (not read by phase 3); q overwrite
        // is fenced by the post-phase-1 barrier of the next branch -> race-free.
    }

    // ---- epilogue: out = blur + (f_1+f_2+f_3)/3  (blur*(1-m) folded via -q_center)
    const float inv3 = 1.f / 3.f;
    const int gi = (h0 + r) * W + (w0 + c);
    out[(n * NC + 0) * HW + gi] = blur_info[(n * NC + 0) * HW + gi] + facc0 * inv3;
    out[(n * NC + 1) * HW + gi] = blur_info[(n * NC + 1) * HW + gi] + facc1 * inv3;
    out[(n * NC + 2) * HW + gi] = blur_info[(n * NC + 2) * HW + gi] + facc2 * inv3;
}

extern "C" void kernel_launch(void* const* d_in, const int* in_sizes, int n_in,
                              void* d_out, int out_size, void* d_ws, size_t ws_size,
                              hipStream_t stream) {
    const float* blur = (const float*)d_in[0];
    float* out = (float*)d_out;

    dim3 grid(W / TW, H / TH, NIMG);     // 16 x 16 x 16 = 4096 blocks
    reblur_fused<<<grid, NTHREADS, 0, stream>>>(
        blur,
        (const float*)d_in[1], (const float*)d_in[2], (const float*)d_in[3],
        (const float*)d_in[4], (const float*)d_in[5], (const float*)d_in[6],
        out);
}